// Round 8
// baseline (5700.107 us; speedup 1.0000x reference)
//
#include <hip/hip_runtime.h>

typedef unsigned short u16;
typedef __attribute__((ext_vector_type(8))) short bf16x8;
typedef __attribute__((ext_vector_type(4))) float f32x4;
typedef __attribute__((ext_vector_type(4))) int i32x4;

#define M_ROWS 8192
#define N_OUT  14336
#define K_IN   4096
#define NTILE  64   // K_IN / 64

__constant__ float NF4_TAB[16] = {
    -1.0f, -0.6961928009986877f, -0.5250730514526367f, -0.39491748809814453f,
    -0.28444138169288635f, -0.18477343022823334f, -0.09105003625154495f, 0.0f,
    0.07958029955625534f, 0.16093020141124725f, 0.24611230194568634f,
    0.33791524171829224f, 0.44070982933044434f, 0.5626170039176941f,
    0.7229568362236023f, 1.0f};

static __device__ __forceinline__ u16 f2bf(float f) {
  union { float f; unsigned u; } v;
  v.f = f;
  unsigned u = v.u;
  unsigned r = (u + 0x7fffu + ((u >> 16) & 1u)) >> 16;
  return (u16)r;
}

static __device__ __forceinline__ void async_load16(const void* g, void* l) {
  __builtin_amdgcn_global_load_lds(
      (const __attribute__((address_space(1))) void*)g,
      (__attribute__((address_space(3))) void*)l, 16, 0, 0);
}

// ---------------------------------------------------------------------------
// Dequant W: 4 packed int32 / thread -> 8 bf16 (one 16B store)
// ---------------------------------------------------------------------------
__global__ __launch_bounds__(256) void dequant_w_kernel(
    const int* __restrict__ wp, const float* __restrict__ wa,
    u16* __restrict__ wout) {
  int t = blockIdx.x * 256 + threadIdx.x;
  const i32x4 p = __builtin_nontemporal_load(
      reinterpret_cast<const i32x4*>(wp) + t);
  float am = wa[t >> 3];
  int v[4] = {p.x, p.y, p.z, p.w};
  union { u16 us[8]; i32x4 v4; } o;
#pragma unroll
  for (int j = 0; j < 4; ++j) {
    o.us[2 * j]     = f2bf(NF4_TAB[(v[j] >> 4) & 15] * am);
    o.us[2 * j + 1] = f2bf(NF4_TAB[v[j] & 15] * am);
  }
  reinterpret_cast<i32x4*>(wout)[t] = o.v4;
}

// ---------------------------------------------------------------------------
// Convert X fp32 -> bf16, 8 elements/thread
// ---------------------------------------------------------------------------
__global__ __launch_bounds__(256) void convert_x_kernel(
    const float* __restrict__ x, u16* __restrict__ xb) {
  int t = blockIdx.x * 256 + threadIdx.x;
  const f32x4 a = __builtin_nontemporal_load(
      reinterpret_cast<const f32x4*>(x) + 2 * t);
  const f32x4 b = __builtin_nontemporal_load(
      reinterpret_cast<const f32x4*>(x) + 2 * t + 1);
  union { u16 us[8]; i32x4 v4; } o;
  o.us[0] = f2bf(a.x); o.us[1] = f2bf(a.y);
  o.us[2] = f2bf(a.z); o.us[3] = f2bf(a.w);
  o.us[4] = f2bf(b.x); o.us[5] = f2bf(b.y);
  o.us[6] = f2bf(b.z); o.us[7] = f2bf(b.w);
  reinterpret_cast<i32x4*>(xb)[t] = o.v4;
}

// ---------------------------------------------------------------------------
// 256x256x64 depth-2 pipelined NT GEMM, 16x16x32 MFMA, ONE barrier per
// K-tile, WAVE-PARITY DESYNC: waves with wr=0 process C-quadrants in order
// (0,0),(0,1),(1,0),(1,1); waves with wr=1 in order (1,1),(1,0),(0,1),(0,0).
// Waves w and w+4 share a SIMD (w&3 mapping) and have opposite wr, so each
// SIMD always has one wave in a read window and one in an MFMA window ->
// LDS pipe (CU-global, ~2800 cyc/tile) and MFMA pipe (~2480 cyc/tile)
// overlap instead of serializing. setprio(1) around MFMA arbitrates.
// Race-safety: identical to R7 (stages write buf[P^1] only; VM(0)+barrier
// per tile; all memory ops pinned between consecutive VM asms).
// ---------------------------------------------------------------------------
__global__ __launch_bounds__(512, 2) void gemm_nf4_256(
    const u16* __restrict__ A, const u16* __restrict__ B,
    float* __restrict__ C, const int* __restrict__ bp,
    const float* __restrict__ ba) {
  constexpr int K = K_IN, N = N_OUT;
  extern __shared__ u16 smem[];
  u16* sA = smem;            // [2][256][64]
  u16* sB = smem + 32768;    // [2][256][64]

  const int tid = threadIdx.x;
  const int w = tid >> 6, lane = tid & 63;
  const int r = lane & 15, kq = lane >> 4;
  const int wr = w >> 2, wc = w & 3;       // 2 x 4 wave grid; parity = wr

  // bijective XCD swizzle (1792 % 8 == 0): contiguous 224-wg chunk per XCD
  int bid = blockIdx.x;
  int cpx = gridDim.x >> 3;
  int wg = (bid & 7) * cpx + (bid >> 3);
  // mt-inner-8 supertile (L2/L3 locality on B panels)
  int grp = wg / 448;                  // 448 = 56*8
  int rem = wg - grp * 448;
  int nt = rem >> 3;
  int mt = grp * 8 + (rem & 7);
  const size_t m0 = (size_t)mt * 256, n0 = (size_t)nt * 256;

  const u16* gA = A + m0 * K;
  const u16* gB = B + n0 * K;

  // read-side swizzled chunk offsets (u16 units) for k-half 0/1
  const int cswz0 = ((kq) ^ (r & 7)) * 8;
  const int cswz1 = ((4 + kq) ^ (r & 7)) * 8;
  // stage-side per-lane global chunk (involution partner of the above)
  const int cg = ((lane & 7) ^ (lane >> 3)) * 8;
  const int jlane = lane >> 3;

  f32x4 acc[8][4] = {};
  bf16x8 aF[4][2], bF[4][2];

#define BAR() __builtin_amdgcn_s_barrier()
#define VM(n) asm volatile("s_waitcnt vmcnt(" #n ")" ::: "memory")

  // P = LDS buffer (compile-time), u = K-tile index (runtime ok)
#define STAGE_A(P, u, mq) do {                                               \
    _Pragma("unroll")                                                        \
    for (int i_ = 0; i_ < 2; ++i_) {                                         \
      int j0_ = (i_ * 8 + w) * 8;                                            \
      int R0_ = (mq) * 64 + ((j0_ >> 6) << 7) + (j0_ & 63);                  \
      int R_ = R0_ + jlane;                                                  \
      async_load16(gA + (size_t)R_ * K + (u) * 64 + cg,                      \
                   sA + (P) * 16384 + R0_ * 64);                             \
    } } while (0)

#define STAGE_B(P, u, nq) do {                                               \
    _Pragma("unroll")                                                        \
    for (int i_ = 0; i_ < 2; ++i_) {                                         \
      int j0_ = (i_ * 8 + w) * 8;                                            \
      int R0_ = (nq) * 32 + ((j0_ >> 5) << 6) + (j0_ & 31);                  \
      int R_ = R0_ + jlane;                                                  \
      async_load16(gB + (size_t)R_ * K + (u) * 64 + cg,                      \
                   sB + (P) * 16384 + R0_ * 64);                             \
    } } while (0)

#define READ_A(P, mq) do {                                                   \
    const u16* ba_ = sA + (P) * 16384 + (wr * 128 + (mq) * 64 + r) * 64;     \
    _Pragma("unroll")                                                        \
    for (int m_ = 0; m_ < 4; ++m_) {                                         \
      aF[m_][0] = *(const bf16x8*)(ba_ + m_ * 1024 + cswz0);                 \
      aF[m_][1] = *(const bf16x8*)(ba_ + m_ * 1024 + cswz1);                 \
    } } while (0)

#define READ_B(P, nq) do {                                                   \
    const u16* bb_ = sB + (P) * 16384 + (wc * 64 + (nq) * 32 + r) * 64;      \
    _Pragma("unroll")                                                        \
    for (int n_ = 0; n_ < 2; ++n_) {                                         \
      bF[(nq) * 2 + n_][0] = *(const bf16x8*)(bb_ + n_ * 1024 + cswz0);      \
      bF[(nq) * 2 + n_][1] = *(const bf16x8*)(bb_ + n_ * 1024 + cswz1);      \
    } } while (0)

#define MFMA_Q(mq, nq) do {                                                  \
    __builtin_amdgcn_s_setprio(1);                                           \
    _Pragma("unroll")                                                        \
    for (int m_ = 0; m_ < 4; ++m_)                                           \
      _Pragma("unroll")                                                      \
      for (int n_ = 0; n_ < 2; ++n_) {                                       \
        acc[(mq) * 4 + m_][(nq) * 2 + n_] =                                  \
            __builtin_amdgcn_mfma_f32_16x16x32_bf16(                         \
                aF[m_][0], bF[(nq) * 2 + n_][0],                             \
                acc[(mq) * 4 + m_][(nq) * 2 + n_], 0, 0, 0);                 \
        acc[(mq) * 4 + m_][(nq) * 2 + n_] =                                  \
            __builtin_amdgcn_mfma_f32_16x16x32_bf16(                         \
                aF[m_][1], bF[(nq) * 2 + n_][1],                             \
                acc[(mq) * 4 + m_][(nq) * 2 + n_], 0, 0, 0);                 \
      }                                                                      \
    __builtin_amdgcn_s_setprio(0);                                           \
  } while (0)

#define STAGES(P, s) do {                                                    \
    STAGE_A((P) ^ 1, (s) + 1, 0); STAGE_A((P) ^ 1, (s) + 1, 1);              \
    STAGE_B((P) ^ 1, (s) + 1, 0); STAGE_B((P) ^ 1, (s) + 1, 1);              \
  } while (0)

  // BODY(tile s, buffer P): barrier-free interior, parity-staggered.
  // parity 0: Q(0,0) Q(0,1) Q(1,0) Q(1,1); parity 1: reversed.
  // Dependency check (parity 1): RA1,RB1 -> Q(1,1); RB0 -> Q(1,0)
  // (aF still q1); RA0 -> Q(0,1) (bF[2..3] still from RB1); Q(0,0). OK.
#define BODY(s, P, DO_STAGE, DO_VMBAR) do {                                  \
    if (wr == 0) {                                                           \
      READ_A(P, 0); READ_B(P, 0);                                            \
      if (DO_STAGE) STAGES(P, s);                                            \
      MFMA_Q(0, 0);                                                          \
      READ_B(P, 1); MFMA_Q(0, 1);                                            \
      READ_A(P, 1); MFMA_Q(1, 0); MFMA_Q(1, 1);                              \
    } else {                                                                 \
      READ_A(P, 1); READ_B(P, 1);                                            \
      if (DO_STAGE) STAGES(P, s);                                            \
      MFMA_Q(1, 1);                                                          \
      READ_B(P, 0); MFMA_Q(1, 0);                                            \
      READ_A(P, 0); MFMA_Q(0, 1); MFMA_Q(0, 0);                              \
    }                                                                        \
    if (DO_VMBAR) { VM(0); BAR(); }                                          \
  } while (0)

  // prologue: stage tile 0 into buf[0]
  STAGE_A(0, 0, 0); STAGE_A(0, 0, 1); STAGE_B(0, 0, 0); STAGE_B(0, 0, 1);
  VM(0); BAR();

  for (int s = 0; s < NTILE - 2; s += 2) {
    BODY(s, 0, 1, 1);
    BODY(s + 1, 1, 1, 1);
  }
  BODY(NTILE - 2, 0, 1, 1);   // stages tile 63 into buf[1]
  BODY(NTILE - 1, 1, 0, 0);   // tail: no stage, no sync

  // epilogue: fused NF4 bias + non-temporal C stores
  // (C/D: col=lane&15, row=(lane>>4)*4+j)
  float bias[4];
#pragma unroll
  for (int ni = 0; ni < 4; ++ni) {
    int col = (int)n0 + wc * 64 + ni * 16 + r;
    int byte = bp[col >> 1];
    int code = (col & 1) ? (byte & 15) : ((byte >> 4) & 15);
    bias[ni] = NF4_TAB[code] * ba[col >> 6];
  }
#pragma unroll
  for (int mi = 0; mi < 8; ++mi) {
    size_t row0 = m0 + wr * 128 + mi * 16 + kq * 4;
#pragma unroll
    for (int ni = 0; ni < 4; ++ni) {
      size_t col = n0 + wc * 64 + ni * 16 + r;
#pragma unroll
      for (int j = 0; j < 4; ++j)
        __builtin_nontemporal_store(acc[mi][ni][j] + bias[ni],
                                    &C[(row0 + j) * N + col]);
    }
  }
#undef BODY
#undef STAGES
#undef MFMA_Q
#undef READ_B
#undef READ_A
#undef STAGE_B
#undef STAGE_A
#undef VM
#undef BAR
}

extern "C" void kernel_launch(void* const* d_in, const int* in_sizes, int n_in,
                              void* d_out, int out_size, void* d_ws,
                              size_t ws_size, hipStream_t stream) {
  const float* x  = (const float*)d_in[0];
  const int* wp   = (const int*)d_in[1];
  const float* wa = (const float*)d_in[2];
  const int* bp   = (const int*)d_in[3];
  const float* ba = (const float*)d_in[4];
  float* out = (float*)d_out;

  u16* Wb = (u16*)d_ws;                     // [N][K] bf16
  u16* Xb = Wb + (size_t)N_OUT * K_IN;      // [M][K] bf16

  dequant_w_kernel<<<28672, 256, 0, stream>>>(wp, wa, Wb);
  convert_x_kernel<<<16384, 256, 0, stream>>>(x, Xb);

  hipFuncSetAttribute(reinterpret_cast<const void*>(gemm_nf4_256),
                      hipFuncAttributeMaxDynamicSharedMemorySize, 131072);
  // 32 m-tiles x 56 n-tiles
  gemm_nf4_256<<<1792, 512, 131072, stream>>>(Xb, Wb, out, bp, ba);
}

// Round 9
// 1147.919 us; speedup vs baseline: 4.9656x; 4.9656x over previous
//
#include <hip/hip_runtime.h>

typedef unsigned short u16;
typedef __attribute__((ext_vector_type(8))) short bf16x8;
typedef __attribute__((ext_vector_type(4))) float f32x4;
typedef __attribute__((ext_vector_type(16))) float f32x16;
typedef __attribute__((ext_vector_type(4))) int i32x4;

#define M_ROWS 8192
#define N_OUT  14336
#define K_IN   4096
#define NTILE  64   // K_IN / 64

__constant__ float NF4_TAB[16] = {
    -1.0f, -0.6961928009986877f, -0.5250730514526367f, -0.39491748809814453f,
    -0.28444138169288635f, -0.18477343022823334f, -0.09105003625154495f, 0.0f,
    0.07958029955625534f, 0.16093020141124725f, 0.24611230194568634f,
    0.33791524171829224f, 0.44070982933044434f, 0.5626170039176941f,
    0.7229568362236023f, 1.0f};

static __device__ __forceinline__ u16 f2bf(float f) {
  union { float f; unsigned u; } v;
  v.f = f;
  unsigned u = v.u;
  unsigned r = (u + 0x7fffu + ((u >> 16) & 1u)) >> 16;
  return (u16)r;
}

static __device__ __forceinline__ void async_load16(const void* g, void* l) {
  __builtin_amdgcn_global_load_lds(
      (const __attribute__((address_space(1))) void*)g,
      (__attribute__((address_space(3))) void*)l, 16, 0, 0);
}

// ---------------------------------------------------------------------------
// Dequant W: 4 packed int32 / thread -> 8 bf16 (one 16B store)
// ---------------------------------------------------------------------------
__global__ __launch_bounds__(256) void dequant_w_kernel(
    const int* __restrict__ wp, const float* __restrict__ wa,
    u16* __restrict__ wout) {
  int t = blockIdx.x * 256 + threadIdx.x;
  const i32x4 p = __builtin_nontemporal_load(
      reinterpret_cast<const i32x4*>(wp) + t);
  float am = wa[t >> 3];
  int v[4] = {p.x, p.y, p.z, p.w};
  union { u16 us[8]; i32x4 v4; } o;
#pragma unroll
  for (int j = 0; j < 4; ++j) {
    o.us[2 * j]     = f2bf(NF4_TAB[(v[j] >> 4) & 15] * am);
    o.us[2 * j + 1] = f2bf(NF4_TAB[v[j] & 15] * am);
  }
  reinterpret_cast<i32x4*>(wout)[t] = o.v4;
}

// ---------------------------------------------------------------------------
// Convert X fp32 -> bf16, 8 elements/thread
// ---------------------------------------------------------------------------
__global__ __launch_bounds__(256) void convert_x_kernel(
    const float* __restrict__ x, u16* __restrict__ xb) {
  int t = blockIdx.x * 256 + threadIdx.x;
  const f32x4 a = __builtin_nontemporal_load(
      reinterpret_cast<const f32x4*>(x) + 2 * t);
  const f32x4 b = __builtin_nontemporal_load(
      reinterpret_cast<const f32x4*>(x) + 2 * t + 1);
  union { u16 us[8]; i32x4 v4; } o;
  o.us[0] = f2bf(a.x); o.us[1] = f2bf(a.y);
  o.us[2] = f2bf(a.z); o.us[3] = f2bf(a.w);
  o.us[4] = f2bf(b.x); o.us[5] = f2bf(b.y);
  o.us[6] = f2bf(b.z); o.us[7] = f2bf(b.w);
  reinterpret_cast<i32x4*>(xb)[t] = o.v4;
}

// ---------------------------------------------------------------------------
// 256x256x64 depth-2 pipelined NT GEMM, 32x32x16 MFMA, 1 barrier/K-tile
// (R7 skeleton, no divergent branches).
// Additive LDS swizzle: LDS[R][slot] holds global 16B-chunk (slot + 5R) mod 8.
//   read slot (lane v=lane&31, hi=lane>>5, k-step ks) = (2ks + hi + 3v) mod 8
//   bank-group = (4R + slot) mod 8 = (7v + 2ks + hi) mod 8 -> bijective on
//   every aligned 8-lane octet (7 coprime 8): perfectly uniform banks at all
//   HW processing granularities (XOR swizzles cannot express this; R4/R5's
//   identical 8.8e7 conflicts were this pattern's 32-row b128 residue).
// Race-safety identical to R7: stages write buf[P^1] only; VM(0)+barrier per
// tile; all memory ops pinned between consecutive VM asms.
// ---------------------------------------------------------------------------
__global__ __launch_bounds__(512, 2) void gemm_nf4_256(
    const u16* __restrict__ A, const u16* __restrict__ B,
    float* __restrict__ C, const int* __restrict__ bp,
    const float* __restrict__ ba) {
  constexpr int K = K_IN, N = N_OUT;
  extern __shared__ u16 smem[];
  u16* sA = smem;            // [2][256][64]
  u16* sB = smem + 32768;    // [2][256][64]

  const int tid = threadIdx.x;
  const int w = tid >> 6, lane = tid & 63;
  const int r32 = lane & 31, hi = lane >> 5;
  const int wr = w >> 2, wc = w & 3;       // 2 x 4 wave grid

  // bijective XCD swizzle (1792 % 8 == 0): contiguous 224-wg chunk per XCD
  int bid = blockIdx.x;
  int cpx = gridDim.x >> 3;
  int wg = (bid & 7) * cpx + (bid >> 3);
  // mt-inner-8 supertile (L2/L3 locality on B panels)
  int grp = wg / 448;                  // 448 = 56*8
  int rem = wg - grp * 448;
  int nt = rem >> 3;
  int mt = grp * 8 + (rem & 7);
  const size_t m0 = (size_t)mt * 256, n0 = (size_t)nt * 256;

  const u16* gA = A + m0 * K;
  const u16* gB = B + n0 * K;

  // read-side swizzled slot offsets (u16 units), one per 16-wide k-step
  int cswz[4];
#pragma unroll
  for (int ks = 0; ks < 4; ++ks)
    cswz[ks] = ((2 * ks + hi + 3 * r32) & 7) * 8;
  // stage-side per-lane global chunk: G = (slot + 5*rowOff) mod 8,
  // slot = lane&7, rowOff = lane>>3 (stage row-bases are multiples of 8)
  const int cg = (((lane & 7) + 5 * (lane >> 3)) & 7) * 8;
  const int jlane = lane >> 3;

  f32x16 acc[4][2] = {};       // [m-tile 32][n-tile 32]
  bf16x8 aF[2][4];             // [m-subtile][k-step]
  bf16x8 bF[2][4];             // [n-quadrant][k-step]

#define BAR() __builtin_amdgcn_s_barrier()
#define VM(n) asm volatile("s_waitcnt vmcnt(" #n ")" ::: "memory")

  // P = LDS buffer (compile-time), u = K-tile index (runtime ok)
#define STAGE_A(P, u, mq) do {                                               \
    _Pragma("unroll")                                                        \
    for (int i_ = 0; i_ < 2; ++i_) {                                         \
      int j0_ = (i_ * 8 + w) * 8;                                            \
      int R0_ = (mq) * 64 + ((j0_ >> 6) << 7) + (j0_ & 63);                  \
      int R_ = R0_ + jlane;                                                  \
      async_load16(gA + (size_t)R_ * K + (u) * 64 + cg,                      \
                   sA + (P) * 16384 + R0_ * 64);                             \
    } } while (0)

#define STAGE_B(P, u, nq) do {                                               \
    _Pragma("unroll")                                                        \
    for (int i_ = 0; i_ < 2; ++i_) {                                         \
      int j0_ = (i_ * 8 + w) * 8;                                            \
      int R0_ = (nq) * 32 + ((j0_ >> 5) << 6) + (j0_ & 31);                  \
      int R_ = R0_ + jlane;                                                  \
      async_load16(gB + (size_t)R_ * K + (u) * 64 + cg,                      \
                   sB + (P) * 16384 + R0_ * 64);                             \
    } } while (0)

  // A-fragments for quadrant mq: rows wr*128 + mq*64 + t_*32 + r32
  // (t_*32 and all bases are multiples of 8 -> slot formula uses r32 only)
#define READ_A(P, mq) do {                                                   \
    const u16* pa_ = sA + (P) * 16384 + (wr * 128 + (mq) * 64 + r32) * 64;   \
    _Pragma("unroll")                                                        \
    for (int t_ = 0; t_ < 2; ++t_)                                           \
      _Pragma("unroll")                                                      \
      for (int ks_ = 0; ks_ < 4; ++ks_)                                      \
        aF[t_][ks_] = *(const bf16x8*)(pa_ + t_ * 2048 + cswz[ks_]);         \
    } while (0)

  // B-fragments for quadrant nq: rows wc*64 + nq*32 + r32
#define READ_B(P, nq) do {                                                   \
    const u16* pb_ = sB + (P) * 16384 + (wc * 64 + (nq) * 32 + r32) * 64;    \
    _Pragma("unroll")                                                        \
    for (int ks_ = 0; ks_ < 4; ++ks_)                                        \
      bF[(nq)][ks_] = *(const bf16x8*)(pb_ + cswz[ks_]);                     \
    } while (0)

#define MFMA_Q(mq, nq) do {                                                  \
    __builtin_amdgcn_s_setprio(1);                                           \
    _Pragma("unroll")                                                        \
    for (int ks_ = 0; ks_ < 4; ++ks_)                                        \
      _Pragma("unroll")                                                      \
      for (int t_ = 0; t_ < 2; ++t_)                                         \
        acc[(mq) * 2 + t_][(nq)] =                                           \
            __builtin_amdgcn_mfma_f32_32x32x16_bf16(                         \
                aF[t_][ks_], bF[(nq)][ks_], acc[(mq) * 2 + t_][(nq)],        \
                0, 0, 0);                                                    \
    __builtin_amdgcn_s_setprio(0);                                           \
  } while (0)

#define STAGES(P, s) do {                                                    \
    STAGE_A((P) ^ 1, (s) + 1, 0); STAGE_A((P) ^ 1, (s) + 1, 1);              \
    STAGE_B((P) ^ 1, (s) + 1, 0); STAGE_B((P) ^ 1, (s) + 1, 1);              \
  } while (0)

  // BODY(tile s, buffer P): barrier-free interior; stages issue early.
#define BODY(s, P, DO_STAGE, DO_VMBAR) do {                                  \
    READ_A(P, 0); READ_B(P, 0);                                              \
    if (DO_STAGE) STAGES(P, s);                                              \
    MFMA_Q(0, 0);                                                            \
    READ_B(P, 1); MFMA_Q(0, 1);                                              \
    READ_A(P, 1); MFMA_Q(1, 0); MFMA_Q(1, 1);                                \
    if (DO_VMBAR) { VM(0); BAR(); }                                          \
  } while (0)

  // prologue: stage tile 0 into buf[0]
  STAGE_A(0, 0, 0); STAGE_A(0, 0, 1); STAGE_B(0, 0, 0); STAGE_B(0, 0, 1);
  VM(0); BAR();

  for (int s = 0; s < NTILE - 2; s += 2) {
    BODY(s, 0, 1, 1);
    BODY(s + 1, 1, 1, 1);
  }
  BODY(NTILE - 2, 0, 1, 1);   // stages tile 63 into buf[1]
  BODY(NTILE - 1, 1, 0, 0);   // tail: no stage, no sync

  // epilogue: fused NF4 bias + non-temporal C stores
  // 32x32 C/D: col = lane&31, row = (reg&3) + 8*(reg>>2) + 4*hi
  float bias[2];
#pragma unroll
  for (int nq = 0; nq < 2; ++nq) {
    int col = (int)n0 + wc * 64 + nq * 32 + r32;
    int byte = bp[col >> 1];
    int code = (col & 1) ? (byte & 15) : ((byte >> 4) & 15);
    bias[nq] = NF4_TAB[code] * ba[col >> 6];
  }
#pragma unroll
  for (int mi = 0; mi < 4; ++mi) {
    size_t rowb = m0 + wr * 128 + mi * 32 + 4 * hi;
#pragma unroll
    for (int nq = 0; nq < 2; ++nq) {
      size_t col = n0 + wc * 64 + nq * 32 + r32;
#pragma unroll
      for (int g = 0; g < 4; ++g)
#pragma unroll
        for (int j = 0; j < 4; ++j)
          __builtin_nontemporal_store(
              acc[mi][nq][g * 4 + j] + bias[nq],
              &C[(rowb + g * 8 + j) * N + col]);
    }
  }
#undef BODY
#undef STAGES
#undef MFMA_Q
#undef READ_B
#undef READ_A
#undef STAGE_B
#undef STAGE_A
#undef VM
#undef BAR
}

extern "C" void kernel_launch(void* const* d_in, const int* in_sizes, int n_in,
                              void* d_out, int out_size, void* d_ws,
                              size_t ws_size, hipStream_t stream) {
  const float* x  = (const float*)d_in[0];
  const int* wp   = (const int*)d_in[1];
  const float* wa = (const float*)d_in[2];
  const int* bp   = (const int*)d_in[3];
  const float* ba = (const float*)d_in[4];
  float* out = (float*)d_out;

  u16* Wb = (u16*)d_ws;                     // [N][K] bf16
  u16* Xb = Wb + (size_t)N_OUT * K_IN;      // [M][K] bf16

  dequant_w_kernel<<<28672, 256, 0, stream>>>(wp, wa, Wb);
  convert_x_kernel<<<16384, 256, 0, stream>>>(x, Xb);

  hipFuncSetAttribute(reinterpret_cast<const void*>(gemm_nf4_256),
                      hipFuncAttributeMaxDynamicSharedMemorySize, 131072);
  // 32 m-tiles x 56 n-tiles
  gemm_nf4_256<<<1792, 512, 131072, stream>>>(Xb, Wb, out, bp, ba);
}

// Round 10
// 854.999 us; speedup vs baseline: 6.6668x; 1.3426x over previous
//
#include <hip/hip_runtime.h>

typedef unsigned short u16;
typedef __attribute__((ext_vector_type(8))) short bf16x8;
typedef __attribute__((ext_vector_type(4))) float f32x4;
typedef __attribute__((ext_vector_type(4))) int i32x4;

#define M_ROWS 8192
#define N_OUT  14336
#define K_IN   4096
#define NTILE  64   // K_IN / 64

__constant__ float NF4_TAB[16] = {
    -1.0f, -0.6961928009986877f, -0.5250730514526367f, -0.39491748809814453f,
    -0.28444138169288635f, -0.18477343022823334f, -0.09105003625154495f, 0.0f,
    0.07958029955625534f, 0.16093020141124725f, 0.24611230194568634f,
    0.33791524171829224f, 0.44070982933044434f, 0.5626170039176941f,
    0.7229568362236023f, 1.0f};

static __device__ __forceinline__ u16 f2bf(float f) {
  union { float f; unsigned u; } v;
  v.f = f;
  unsigned u = v.u;
  unsigned r = (u + 0x7fffu + ((u >> 16) & 1u)) >> 16;
  return (u16)r;
}

static __device__ __forceinline__ void async_load16(const void* g, void* l) {
  __builtin_amdgcn_global_load_lds(
      (const __attribute__((address_space(1))) void*)g,
      (__attribute__((address_space(3))) void*)l, 16, 0, 0);
}

// ---------------------------------------------------------------------------
// Dequant W: 4 packed int32 / thread -> 8 bf16 (one 16B store)
// ---------------------------------------------------------------------------
__global__ __launch_bounds__(256) void dequant_w_kernel(
    const int* __restrict__ wp, const float* __restrict__ wa,
    u16* __restrict__ wout) {
  int t = blockIdx.x * 256 + threadIdx.x;
  const i32x4 p = __builtin_nontemporal_load(
      reinterpret_cast<const i32x4*>(wp) + t);
  float am = wa[t >> 3];
  int v[4] = {p.x, p.y, p.z, p.w};
  union { u16 us[8]; i32x4 v4; } o;
#pragma unroll
  for (int j = 0; j < 4; ++j) {
    o.us[2 * j]     = f2bf(NF4_TAB[(v[j] >> 4) & 15] * am);
    o.us[2 * j + 1] = f2bf(NF4_TAB[v[j] & 15] * am);
  }
  reinterpret_cast<i32x4*>(wout)[t] = o.v4;
}

// ---------------------------------------------------------------------------
// Convert X fp32 -> bf16, 8 elements/thread
// ---------------------------------------------------------------------------
__global__ __launch_bounds__(256) void convert_x_kernel(
    const float* __restrict__ x, u16* __restrict__ xb) {
  int t = blockIdx.x * 256 + threadIdx.x;
  const f32x4 a = __builtin_nontemporal_load(
      reinterpret_cast<const f32x4*>(x) + 2 * t);
  const f32x4 b = __builtin_nontemporal_load(
      reinterpret_cast<const f32x4*>(x) + 2 * t + 1);
  union { u16 us[8]; i32x4 v4; } o;
  o.us[0] = f2bf(a.x); o.us[1] = f2bf(a.y);
  o.us[2] = f2bf(a.z); o.us[3] = f2bf(a.w);
  o.us[4] = f2bf(b.x); o.us[5] = f2bf(b.y);
  o.us[6] = f2bf(b.z); o.us[7] = f2bf(b.w);
  reinterpret_cast<i32x4*>(xb)[t] = o.v4;
}

// ---------------------------------------------------------------------------
// 256x256x64 8-phase pipelined NT GEMM, 16x16x32 MFMA (R3 structure — the
// best-measured variant: 853 us total, 0 bank conflicts, MfmaUtil 54.5).
// Change vs R3: C stores are PLAIN (not nontemporal) — NT bypassed L2
// write-combining and amplified the 4-row x 64B store pattern to 600 MB of
// HBM writes vs 470 MB ideal (R2 plain stores measured 510 MB; L3 panel
// eviction from cached C was measured-neutral on duration).
// ---------------------------------------------------------------------------
__global__ __launch_bounds__(512, 2) void gemm_nf4_256(
    const u16* __restrict__ A, const u16* __restrict__ B,
    float* __restrict__ C, const int* __restrict__ bp,
    const float* __restrict__ ba) {
  constexpr int K = K_IN, N = N_OUT;
  extern __shared__ u16 smem[];
  u16* sA = smem;            // [2][256][64]
  u16* sB = smem + 32768;    // [2][256][64]

  const int tid = threadIdx.x;
  const int w = tid >> 6, lane = tid & 63;
  const int r = lane & 15, kq = lane >> 4;
  const int wr = w >> 2, wc = w & 3;       // 2 x 4 wave grid

  // bijective XCD swizzle (1792 % 8 == 0): contiguous 224-wg chunk per XCD
  int bid = blockIdx.x;
  int cpx = gridDim.x >> 3;
  int wg = (bid & 7) * cpx + (bid >> 3);
  // mt-inner-8 supertile (L2/L3 locality on B panels)
  int grp = wg / 448;                  // 448 = 56*8
  int rem = wg - grp * 448;
  int nt = rem >> 3;
  int mt = grp * 8 + (rem & 7);
  const size_t m0 = (size_t)mt * 256, n0 = (size_t)nt * 256;

  const u16* gA = A + m0 * K;
  const u16* gB = B + n0 * K;

  // read-side swizzled chunk offsets (u16 units) for k-half 0/1
  const int cswz0 = ((kq) ^ (r & 7)) * 8;
  const int cswz1 = ((4 + kq) ^ (r & 7)) * 8;
  // stage-side per-lane global chunk (involution partner of the above)
  const int cg = ((lane & 7) ^ (lane >> 3)) * 8;
  const int jlane = lane >> 3;

  f32x4 acc[8][4] = {};
  bf16x8 aF[4][2], bF[4][2];

#define FENCE() asm volatile("" ::: "memory")
#define BAR() do { __builtin_amdgcn_s_barrier(); FENCE(); } while (0)
#define LGKM8() asm volatile("s_waitcnt lgkmcnt(8)" ::: "memory")
#define LGKM0() asm volatile("s_waitcnt lgkmcnt(0)" ::: "memory")
#define VM(n) asm volatile("s_waitcnt vmcnt(" #n ")" ::: "memory")

#define STAGE_A(u, mq) do {                                                  \
    int P_ = (u) & 1;                                                        \
    _Pragma("unroll")                                                        \
    for (int i_ = 0; i_ < 2; ++i_) {                                         \
      int j0_ = (i_ * 8 + w) * 8;                                            \
      int R0_ = (mq) * 64 + ((j0_ >> 6) << 7) + (j0_ & 63);                  \
      int R_ = R0_ + jlane;                                                  \
      async_load16(gA + (size_t)R_ * K + (u) * 64 + cg,                      \
                   sA + P_ * 16384 + R0_ * 64);                              \
    } } while (0)

#define STAGE_B(u, nq) do {                                                  \
    int P_ = (u) & 1;                                                        \
    _Pragma("unroll")                                                        \
    for (int i_ = 0; i_ < 2; ++i_) {                                         \
      int j0_ = (i_ * 8 + w) * 8;                                            \
      int R0_ = (nq) * 32 + ((j0_ >> 5) << 6) + (j0_ & 31);                  \
      int R_ = R0_ + jlane;                                                  \
      async_load16(gB + (size_t)R_ * K + (u) * 64 + cg,                      \
                   sB + P_ * 16384 + R0_ * 64);                              \
    } } while (0)

#define READ_A(P, mq) do {                                                   \
    const u16* ba_ = sA + (P) * 16384 + (wr * 128 + (mq) * 64 + r) * 64;     \
    _Pragma("unroll")                                                        \
    for (int m_ = 0; m_ < 4; ++m_) {                                         \
      aF[m_][0] = *(const bf16x8*)(ba_ + m_ * 1024 + cswz0);                 \
      aF[m_][1] = *(const bf16x8*)(ba_ + m_ * 1024 + cswz1);                 \
    } } while (0)

#define READ_B(P, nq) do {                                                   \
    const u16* bb_ = sB + (P) * 16384 + (wc * 64 + (nq) * 32 + r) * 64;      \
    _Pragma("unroll")                                                        \
    for (int n_ = 0; n_ < 2; ++n_) {                                         \
      bF[(nq) * 2 + n_][0] = *(const bf16x8*)(bb_ + n_ * 1024 + cswz0);      \
      bF[(nq) * 2 + n_][1] = *(const bf16x8*)(bb_ + n_ * 1024 + cswz1);      \
    } } while (0)

#define MFMA_Q(mq, nq) do {                                                  \
    __builtin_amdgcn_s_setprio(1);                                           \
    _Pragma("unroll")                                                        \
    for (int m_ = 0; m_ < 4; ++m_)                                           \
      _Pragma("unroll")                                                      \
      for (int n_ = 0; n_ < 2; ++n_) {                                       \
        acc[(mq) * 4 + m_][(nq) * 2 + n_] =                                  \
            __builtin_amdgcn_mfma_f32_16x16x32_bf16(                         \
                aF[m_][0], bF[(nq) * 2 + n_][0],                             \
                acc[(mq) * 4 + m_][(nq) * 2 + n_], 0, 0, 0);                 \
        acc[(mq) * 4 + m_][(nq) * 2 + n_] =                                  \
            __builtin_amdgcn_mfma_f32_16x16x32_bf16(                         \
                aF[m_][1], bF[(nq) * 2 + n_][1],                             \
                acc[(mq) * 4 + m_][(nq) * 2 + n_], 0, 0, 0);                 \
      }                                                                      \
    __builtin_amdgcn_s_setprio(0);                                           \
  } while (0)

  // TILE: 4 phases; stages: p1 -> (s+1).A1, p2 -> (s+2).A0, p3 -> (s+2).B0,
  // p4 -> (s+2).B1. Every staged region's last read was >=1 barrier before
  // the stage issue (race-free); vmcnt(6) at p4 lands all of tile s+1.
#define TILE(s, P, DO_P1, DO_P234, VMSTMT) do {                              \
    READ_A(P, 0); READ_B(P, 0);                                              \
    if (DO_P1) STAGE_A((s) + 1, 1);                                          \
    LGKM8();                                                                 \
    BAR(); LGKM0(); MFMA_Q(0, 0); BAR();                                     \
    READ_B(P, 1);                                                            \
    if (DO_P234) STAGE_A((s) + 2, 0);                                        \
    BAR(); LGKM0(); MFMA_Q(0, 1); BAR();                                     \
    READ_A(P, 1);                                                            \
    if (DO_P234) STAGE_B((s) + 2, 0);                                        \
    BAR(); LGKM0(); MFMA_Q(1, 0); BAR();                                     \
    if (DO_P234) STAGE_B((s) + 2, 1);                                        \
    BAR(); MFMA_Q(1, 1);                                                     \
    VMSTMT; BAR();                                                           \
  } while (0)

  // prologue: tile0 fully + tile1 {A0,B0,B1}; tile1.A1 comes at s=0 p1
  STAGE_A(0, 0); STAGE_B(0, 0); STAGE_B(0, 1); STAGE_A(0, 1);
  STAGE_A(1, 0); STAGE_B(1, 0); STAGE_B(1, 1);
  VM(6); BAR();

  for (int s = 0; s < NTILE - 2; s += 2) {
    TILE(s, 0, 1, 1, VM(6));
    TILE((s) + 1, 1, 1, 1, VM(6));
  }
  TILE(NTILE - 2, 0, 1, 0, VM(0));   // stage 63.A1 only; drain
  TILE(NTILE - 1, 1, 0, 0, (void)0);

  // epilogue: fused NF4 bias + PLAIN C stores (L2 write-combining merges the
  // adjacent 64B segments into full lines; NT bypassed it -> +28% writes)
  // (C/D: col=lane&15, row=(lane>>4)*4+j)
  float bias[4];
#pragma unroll
  for (int ni = 0; ni < 4; ++ni) {
    int col = (int)n0 + wc * 64 + ni * 16 + r;
    int byte = bp[col >> 1];
    int code = (col & 1) ? (byte & 15) : ((byte >> 4) & 15);
    bias[ni] = NF4_TAB[code] * ba[col >> 6];
  }
#pragma unroll
  for (int mi = 0; mi < 8; ++mi) {
    size_t row0 = m0 + wr * 128 + mi * 16 + kq * 4;
#pragma unroll
    for (int ni = 0; ni < 4; ++ni) {
      size_t col = n0 + wc * 64 + ni * 16 + r;
#pragma unroll
      for (int j = 0; j < 4; ++j)
        C[(row0 + j) * N + col] = acc[mi][ni][j] + bias[ni];
    }
  }
#undef TILE
#undef MFMA_Q
#undef READ_B
#undef READ_A
#undef STAGE_B
#undef STAGE_A
#undef VM
#undef LGKM0
#undef LGKM8
#undef BAR
#undef FENCE
}

extern "C" void kernel_launch(void* const* d_in, const int* in_sizes, int n_in,
                              void* d_out, int out_size, void* d_ws,
                              size_t ws_size, hipStream_t stream) {
  const float* x  = (const float*)d_in[0];
  const int* wp   = (const int*)d_in[1];
  const float* wa = (const float*)d_in[2];
  const int* bp   = (const int*)d_in[3];
  const float* ba = (const float*)d_in[4];
  float* out = (float*)d_out;

  u16* Wb = (u16*)d_ws;                     // [N][K] bf16
  u16* Xb = Wb + (size_t)N_OUT * K_IN;      // [M][K] bf16

  dequant_w_kernel<<<28672, 256, 0, stream>>>(wp, wa, Wb);
  convert_x_kernel<<<16384, 256, 0, stream>>>(x, Xb);

  hipFuncSetAttribute(reinterpret_cast<const void*>(gemm_nf4_256),
                      hipFuncAttributeMaxDynamicSharedMemorySize, 131072);
  // 32 m-tiles x 56 n-tiles
  gemm_nf4_256<<<1792, 512, 131072, stream>>>(Xb, Wb, out, bp, ba);
}

// Round 11
// 851.995 us; speedup vs baseline: 6.6903x; 1.0035x over previous
//
#include <hip/hip_runtime.h>

typedef unsigned short u16;
typedef __attribute__((ext_vector_type(8))) short bf16x8;
typedef __attribute__((ext_vector_type(4))) float f32x4;
typedef __attribute__((ext_vector_type(4))) int i32x4;

#define M_ROWS 8192
#define N_OUT  14336
#define K_IN   4096
#define NTILE  64   // K_IN / 64

__constant__ float NF4_TAB[16] = {
    -1.0f, -0.6961928009986877f, -0.5250730514526367f, -0.39491748809814453f,
    -0.28444138169288635f, -0.18477343022823334f, -0.09105003625154495f, 0.0f,
    0.07958029955625534f, 0.16093020141124725f, 0.24611230194568634f,
    0.33791524171829224f, 0.44070982933044434f, 0.5626170039176941f,
    0.7229568362236023f, 1.0f};

static __device__ __forceinline__ u16 f2bf(float f) {
  union { float f; unsigned u; } v;
  v.f = f;
  unsigned u = v.u;
  unsigned r = (u + 0x7fffu + ((u >> 16) & 1u)) >> 16;
  return (u16)r;
}

static __device__ __forceinline__ void async_load16(const void* g, void* l) {
  __builtin_amdgcn_global_load_lds(
      (const __attribute__((address_space(1))) void*)g,
      (__attribute__((address_space(3))) void*)l, 16, 0, 0);
}

// ---------------------------------------------------------------------------
// Dequant W: 4 packed int32 / thread -> 8 bf16 (one 16B store)
// ---------------------------------------------------------------------------
__global__ __launch_bounds__(256) void dequant_w_kernel(
    const int* __restrict__ wp, const float* __restrict__ wa,
    u16* __restrict__ wout) {
  int t = blockIdx.x * 256 + threadIdx.x;
  const i32x4 p = __builtin_nontemporal_load(
      reinterpret_cast<const i32x4*>(wp) + t);
  float am = wa[t >> 3];
  int v[4] = {p.x, p.y, p.z, p.w};
  union { u16 us[8]; i32x4 v4; } o;
#pragma unroll
  for (int j = 0; j < 4; ++j) {
    o.us[2 * j]     = f2bf(NF4_TAB[(v[j] >> 4) & 15] * am);
    o.us[2 * j + 1] = f2bf(NF4_TAB[v[j] & 15] * am);
  }
  reinterpret_cast<i32x4*>(wout)[t] = o.v4;
}

// ---------------------------------------------------------------------------
// Convert X fp32 -> bf16, 8 elements/thread
// ---------------------------------------------------------------------------
__global__ __launch_bounds__(256) void convert_x_kernel(
    const float* __restrict__ x, u16* __restrict__ xb) {
  int t = blockIdx.x * 256 + threadIdx.x;
  const f32x4 a = __builtin_nontemporal_load(
      reinterpret_cast<const f32x4*>(x) + 2 * t);
  const f32x4 b = __builtin_nontemporal_load(
      reinterpret_cast<const f32x4*>(x) + 2 * t + 1);
  union { u16 us[8]; i32x4 v4; } o;
  o.us[0] = f2bf(a.x); o.us[1] = f2bf(a.y);
  o.us[2] = f2bf(a.z); o.us[3] = f2bf(a.w);
  o.us[4] = f2bf(b.x); o.us[5] = f2bf(b.y);
  o.us[6] = f2bf(b.z); o.us[7] = f2bf(b.w);
  reinterpret_cast<i32x4*>(xb)[t] = o.v4;
}

// ---------------------------------------------------------------------------
// 256x256x64 8-phase pipelined NT GEMM, 16x16x32 MFMA (R3/R10 structure:
// best measured, 0 bank conflicts, MfmaUtil ~54).
// R11 micro-opts: (1) hoisted per-lane stage base pointers (kills per-tile
// 64-bit R*K mads -> lower VALUBusy); (2) stage issued at phase top (earlier
// VMEM issue); (3) final tile fused with per-quadrant C stores (no interior
// barriers needed: buffer fully drained at tile-62's VM(0)) so store issue
// overlaps the last MFMA clusters. Plain C stores (R10: -90 MB HBM writes).
// ---------------------------------------------------------------------------
__global__ __launch_bounds__(512, 2) void gemm_nf4_256(
    const u16* __restrict__ A, const u16* __restrict__ B,
    float* __restrict__ C, const int* __restrict__ bp,
    const float* __restrict__ ba) {
  constexpr int K = K_IN, N = N_OUT;
  extern __shared__ u16 smem[];
  u16* sA = smem;            // [2][256][64]
  u16* sB = smem + 32768;    // [2][256][64]

  const int tid = threadIdx.x;
  const int w = tid >> 6, lane = tid & 63;
  const int r = lane & 15, kq = lane >> 4;
  const int wr = w >> 2, wc = w & 3;       // 2 x 4 wave grid

  // bijective XCD swizzle (1792 % 8 == 0): contiguous 224-wg chunk per XCD
  int bid = blockIdx.x;
  int cpx = gridDim.x >> 3;
  int wg = (bid & 7) * cpx + (bid >> 3);
  // mt-inner-8 supertile (L2/L3 locality on B panels)
  int grp = wg / 448;                  // 448 = 56*8
  int rem = wg - grp * 448;
  int nt = rem >> 3;
  int mt = grp * 8 + (rem & 7);
  const size_t m0 = (size_t)mt * 256, n0 = (size_t)nt * 256;

  const u16* gA = A + m0 * K;
  const u16* gB = B + n0 * K;

  // read-side swizzled chunk offsets (u16 units) for k-half 0/1
  const int cswz0 = ((kq) ^ (r & 7)) * 8;
  const int cswz1 = ((4 + kq) ^ (r & 7)) * 8;
  // stage-side per-lane global chunk (involution partner of the above)
  const int cg = ((lane & 7) ^ (lane >> 3)) * 8;
  const int jlane = lane >> 3;

  // hoisted stage bases: index = mq*2+i_ (A) / nq*2+i_ (B); loop-invariant
  const u16* stA[4]; const u16* stB[4];
  int ldA[4], ldB[4];
#pragma unroll
  for (int i_ = 0; i_ < 2; ++i_) {
    int j0_ = (i_ * 8 + w) * 8;
#pragma unroll
    for (int mq_ = 0; mq_ < 2; ++mq_) {
      int R0_ = mq_ * 64 + ((j0_ >> 6) << 7) + (j0_ & 63);
      stA[mq_ * 2 + i_] = gA + (size_t)(R0_ + jlane) * K + cg;
      ldA[mq_ * 2 + i_] = R0_ * 64;
    }
#pragma unroll
    for (int nq_ = 0; nq_ < 2; ++nq_) {
      int R0_ = nq_ * 32 + ((j0_ >> 5) << 6) + (j0_ & 31);
      stB[nq_ * 2 + i_] = gB + (size_t)(R0_ + jlane) * K + cg;
      ldB[nq_ * 2 + i_] = R0_ * 64;
    }
  }

  f32x4 acc[8][4] = {};
  bf16x8 aF[4][2], bF[4][2];

#define FENCE() asm volatile("" ::: "memory")
#define BAR() do { __builtin_amdgcn_s_barrier(); FENCE(); } while (0)
#define LGKM0() asm volatile("s_waitcnt lgkmcnt(0)" ::: "memory")
#define VM(n) asm volatile("s_waitcnt vmcnt(" #n ")" ::: "memory")

#define STAGE_A(u, mq) do {                                                  \
    int P_ = (u) & 1;                                                        \
    _Pragma("unroll")                                                        \
    for (int i_ = 0; i_ < 2; ++i_)                                           \
      async_load16(stA[(mq) * 2 + i_] + (u) * 64,                            \
                   sA + P_ * 16384 + ldA[(mq) * 2 + i_]);                    \
    } while (0)

#define STAGE_B(u, nq) do {                                                  \
    int P_ = (u) & 1;                                                        \
    _Pragma("unroll")                                                        \
    for (int i_ = 0; i_ < 2; ++i_)                                           \
      async_load16(stB[(nq) * 2 + i_] + (u) * 64,                            \
                   sB + P_ * 16384 + ldB[(nq) * 2 + i_]);                    \
    } while (0)

#define READ_A(P, mq) do {                                                   \
    const u16* ba_ = sA + (P) * 16384 + (wr * 128 + (mq) * 64 + r) * 64;     \
    _Pragma("unroll")                                                        \
    for (int m_ = 0; m_ < 4; ++m_) {                                         \
      aF[m_][0] = *(const bf16x8*)(ba_ + m_ * 1024 + cswz0);                 \
      aF[m_][1] = *(const bf16x8*)(ba_ + m_ * 1024 + cswz1);                 \
    } } while (0)

#define READ_B(P, nq) do {                                                   \
    const u16* bb_ = sB + (P) * 16384 + (wc * 64 + (nq) * 32 + r) * 64;      \
    _Pragma("unroll")                                                        \
    for (int n_ = 0; n_ < 2; ++n_) {                                         \
      bF[(nq) * 2 + n_][0] = *(const bf16x8*)(bb_ + n_ * 1024 + cswz0);      \
      bF[(nq) * 2 + n_][1] = *(const bf16x8*)(bb_ + n_ * 1024 + cswz1);      \
    } } while (0)

#define MFMA_Q(mq, nq) do {                                                  \
    __builtin_amdgcn_s_setprio(1);                                           \
    _Pragma("unroll")                                                        \
    for (int m_ = 0; m_ < 4; ++m_)                                           \
      _Pragma("unroll")                                                      \
      for (int n_ = 0; n_ < 2; ++n_) {                                       \
        acc[(mq) * 4 + m_][(nq) * 2 + n_] =                                  \
            __builtin_amdgcn_mfma_f32_16x16x32_bf16(                         \
                aF[m_][0], bF[(nq) * 2 + n_][0],                             \
                acc[(mq) * 4 + m_][(nq) * 2 + n_], 0, 0, 0);                 \
        acc[(mq) * 4 + m_][(nq) * 2 + n_] =                                  \
            __builtin_amdgcn_mfma_f32_16x16x32_bf16(                         \
                aF[m_][1], bF[(nq) * 2 + n_][1],                             \
                acc[(mq) * 4 + m_][(nq) * 2 + n_], 0, 0, 0);                 \
      }                                                                      \
    __builtin_amdgcn_s_setprio(0);                                           \
  } while (0)

  // TILE: 4 phases; stage at phase TOP (earlier VMEM issue); stages:
  // p1 -> (s+1).A1, p2 -> (s+2).A0, p3 -> (s+2).B0, p4 -> (s+2).B1.
  // vmcnt(6) at p4 lands all of tile s+1.
#define TILE(s, P, DO_P1, DO_P234, VMSTMT) do {                              \
    if (DO_P1) STAGE_A((s) + 1, 1);                                          \
    READ_A(P, 0); READ_B(P, 0);                                              \
    BAR(); LGKM0(); MFMA_Q(0, 0); BAR();                                     \
    if (DO_P234) STAGE_A((s) + 2, 0);                                        \
    READ_B(P, 1);                                                            \
    BAR(); LGKM0(); MFMA_Q(0, 1); BAR();                                     \
    if (DO_P234) STAGE_B((s) + 2, 0);                                        \
    READ_A(P, 1);                                                            \
    BAR(); LGKM0(); MFMA_Q(1, 0); BAR();                                     \
    if (DO_P234) STAGE_B((s) + 2, 1);                                        \
    BAR(); MFMA_Q(1, 1);                                                     \
    VMSTMT; BAR();                                                           \
  } while (0)

#define STORE_Q(mq, nq) do {                                                 \
    _Pragma("unroll")                                                        \
    for (int m_ = 0; m_ < 4; ++m_) {                                         \
      size_t row0 = m0 + wr * 128 + ((mq) * 4 + m_) * 16 + kq * 4;           \
      _Pragma("unroll")                                                      \
      for (int n_ = 0; n_ < 2; ++n_) {                                       \
        size_t col = n0 + wc * 64 + ((nq) * 2 + n_) * 16 + r;                \
        _Pragma("unroll")                                                    \
        for (int j = 0; j < 4; ++j)                                          \
          C[(row0 + j) * N + col] =                                          \
              acc[(mq) * 4 + m_][(nq) * 2 + n_][j] + bias[(nq) * 2 + n_];    \
      }                                                                      \
    } } while (0)

  // prologue: tile0 fully + tile1 {A0,B0,B1}; tile1.A1 comes at s=0 p1
  STAGE_A(0, 0); STAGE_B(0, 0); STAGE_B(0, 1); STAGE_A(0, 1);
  STAGE_A(1, 0); STAGE_B(1, 0); STAGE_B(1, 1);
  VM(6); BAR();

  for (int s = 0; s < NTILE - 2; s += 2) {
    TILE(s, 0, 1, 1, VM(6));
    TILE((s) + 1, 1, 1, 1, VM(6));
  }

  // bias dequant issued before the final tile (overlaps its waits)
  float bias[4];
#pragma unroll
  for (int ni = 0; ni < 4; ++ni) {
    int col = (int)n0 + wc * 64 + ni * 16 + r;
    int byte = bp[col >> 1];
    int code = (col & 1) ? (byte & 15) : ((byte >> 4) & 15);
    bias[ni] = NF4_TAB[code] * ba[col >> 6];
  }

  TILE(NTILE - 2, 0, 1, 0, VM(0));   // stage 63.A1 only; full drain

  // final tile (s=63, buf 1): fully landed + all waves synced -> no interior
  // barriers; fuse per-quadrant stores right after each quadrant's last MFMA.
  READ_A(1, 0); READ_B(1, 0);
  MFMA_Q(0, 0); STORE_Q(0, 0);
  READ_B(1, 1);
  MFMA_Q(0, 1); STORE_Q(0, 1);
  READ_A(1, 1);
  MFMA_Q(1, 0); STORE_Q(1, 0);
  MFMA_Q(1, 1); STORE_Q(1, 1);

#undef STORE_Q
#undef TILE
#undef MFMA_Q
#undef READ_B
#undef READ_A
#undef STAGE_B
#undef STAGE_A
#undef VM
#undef LGKM0
#undef BAR
#undef FENCE
}

extern "C" void kernel_launch(void* const* d_in, const int* in_sizes, int n_in,
                              void* d_out, int out_size, void* d_ws,
                              size_t ws_size, hipStream_t stream) {
  const float* x  = (const float*)d_in[0];
  const int* wp   = (const int*)d_in[1];
  const float* wa = (const float*)d_in[2];
  const int* bp   = (const int*)d_in[3];
  const float* ba = (const float*)d_in[4];
  float* out = (float*)d_out;

  u16* Wb = (u16*)d_ws;                     // [N][K] bf16
  u16* Xb = Wb + (size_t)N_OUT * K_IN;      // [M][K] bf16

  dequant_w_kernel<<<28672, 256, 0, stream>>>(wp, wa, Wb);
  convert_x_kernel<<<16384, 256, 0, stream>>>(x, Xb);

  hipFuncSetAttribute(reinterpret_cast<const void*>(gemm_nf4_256),
                      hipFuncAttributeMaxDynamicSharedMemorySize, 131072);
  // 32 m-tiles x 56 n-tiles
  gemm_nf4_256<<<1792, 512, 131072, stream>>>(Xb, Wb, out, bp, ba);
}